// Round 3
// baseline (378.559 us; speedup 1.0000x reference)
//
#include <hip/hip_runtime.h>
#include <stdint.h>

// FactoredAttention: x[16384,1024] f32 -> qkv GEMM (bf16 compute) ->
// 16-block causal attn -> proj GEMM -> out f32.
// I/O is FLOAT32 (npz-size evidence); bf16 is compute/intermediate only.
// ws: qkv bf16 (16384*3072) | w_attnT bf16 (3072*1024) | w_projT bf16 (1024*1024)

typedef __bf16 bf16x8 __attribute__((ext_vector_type(8)));
typedef short short8 __attribute__((ext_vector_type(8)));
typedef float f32x4 __attribute__((ext_vector_type(4)));
typedef unsigned short ushort4v __attribute__((ext_vector_type(4)));
typedef unsigned short ushort8v __attribute__((ext_vector_type(8)));

#define GLOAD_LDS16(g, l)                                                      \
  __builtin_amdgcn_global_load_lds(                                            \
      (const __attribute__((address_space(1))) void*)(g),                      \
      (__attribute__((address_space(3))) void*)(l), 16, 0, 0)

static __device__ __forceinline__ f32x4 mfma16(short8 a, short8 b, f32x4 c) {
  return __builtin_amdgcn_mfma_f32_16x16x32_bf16(
      __builtin_bit_cast(bf16x8, a), __builtin_bit_cast(bf16x8, b), c, 0, 0, 0);
}

static __device__ __forceinline__ unsigned short f2bf(float f) {
  unsigned u = __builtin_bit_cast(unsigned, f);
  u += 0x7FFFu + ((u >> 16) & 1u);
  return (unsigned short)(u >> 16);
}

// ---------------------------------------------------------------------------
// Transpose + convert: in f32 [K][N] -> out bf16 [N][K].  grid (N/64, K/64).
// ---------------------------------------------------------------------------
__global__ __launch_bounds__(256) void transposeW(
    const float* __restrict__ in, unsigned short* __restrict__ out,
    int K, int N) {
  __shared__ float tile[64][68];
  int tn = blockIdx.x * 64, tk = blockIdx.y * 64;
  int tid = threadIdx.x;
#pragma unroll
  for (int i = 0; i < 4; ++i) {
    int ch = i * 256 + tid;
    int r = ch >> 4, c4 = (ch & 15) << 2;
    f32x4 v = *(const f32x4*)(in + (size_t)(tk + r) * N + tn + c4);
    tile[r][c4] = v[0]; tile[r][c4 + 1] = v[1];
    tile[r][c4 + 2] = v[2]; tile[r][c4 + 3] = v[3];
  }
  __syncthreads();
#pragma unroll
  for (int i = 0; i < 4; ++i) {
    int ch = i * 256 + tid;
    int r = ch >> 4, c4 = (ch & 15) << 2;
    ushort4v v;
    v[0] = f2bf(tile[c4][r]);     v[1] = f2bf(tile[c4 + 1][r]);
    v[2] = f2bf(tile[c4 + 2][r]); v[3] = f2bf(tile[c4 + 3][r]);
    *(ushort4v*)(out + (size_t)(tn + r) * K + tk + c4) = v;
  }
}

// ---------------------------------------------------------------------------
// C[M][N] = A[M][K] * Bt[N][K]^T + bias(f32).  128x128 tile, BK=64, 2x2 waves.
// A_F32: A is f32, register-staged + converted, ds_write to swizzled LDS.
// else:  A is bf16, global_load_lds with inverse-swizzled source.
// B always bf16 via global_load_lds.  C_F32 selects output dtype.
// LDS XOR-swizzle: byte ^= (row&7)<<4.  grid.x % 8 == 0 (XCD swizzle).
// ---------------------------------------------------------------------------
template <bool A_F32, bool C_F32>
__global__ __launch_bounds__(256) void gemm_bt(
    const void* __restrict__ Aptr, int lda,
    const unsigned short* __restrict__ Bt, int ldb,
    const float* __restrict__ bias,
    void* __restrict__ Cptr, int ldc,
    int Ntiles, int K) {
  __shared__ unsigned short sA[128 * 64];
  __shared__ unsigned short sB[128 * 64];
  int bid = blockIdx.x;
  int nwg = gridDim.x;
  int swz = (bid & 7) * (nwg >> 3) + (bid >> 3);
  int bm = swz / Ntiles, bn = swz % Ntiles;
  int tid = threadIdx.x;
  int lane = tid & 63, wave = tid >> 6;
  int wr = wave >> 1, wc = wave & 1;
  int g = lane >> 4, cx = lane & 15;

  const float* srcAf[4];
  unsigned dstAswz[4];
  const unsigned short* srcA16[4];
  unsigned short* dstA[4];
  const unsigned short* srcB[4];
  unsigned short* dstB[4];
#pragma unroll
  for (int i = 0; i < 4; ++i) {
    int c = i * 256 + tid;
    int r = c >> 3, pc = c & 7;
    int cc = pc ^ (r & 7);
    if (A_F32) {
      srcAf[i] = (const float*)Aptr + (size_t)(bm * 128 + r) * lda + pc * 8;
      dstAswz[i] = (unsigned)((r * 128 + pc * 16) ^ ((r & 7) << 4));
    } else {
      srcA16[i] = (const unsigned short*)Aptr + (size_t)(bm * 128 + r) * lda + cc * 8;
      dstA[i] = sA + (i * 256 + wave * 64) * 8;
    }
    srcB[i] = Bt + (size_t)(bn * 128 + r) * ldb + cc * 8;
    dstB[i] = sB + (i * 256 + wave * 64) * 8;
  }

  f32x4 zero4 = {0.f, 0.f, 0.f, 0.f};
  f32x4 acc[4][4];
#pragma unroll
  for (int a = 0; a < 4; ++a)
#pragma unroll
    for (int b = 0; b < 4; ++b) acc[a][b] = zero4;

  for (int kt = 0; kt < K; kt += 64) {
#pragma unroll
    for (int i = 0; i < 4; ++i) {
      GLOAD_LDS16(srcB[i] + kt, dstB[i]);
      if (A_F32) {
        f32x4 lo = *(const f32x4*)(srcAf[i] + kt);
        f32x4 hi = *(const f32x4*)(srcAf[i] + kt + 4);
        ushort8v v;
        v[0] = f2bf(lo[0]); v[1] = f2bf(lo[1]); v[2] = f2bf(lo[2]); v[3] = f2bf(lo[3]);
        v[4] = f2bf(hi[0]); v[5] = f2bf(hi[1]); v[6] = f2bf(hi[2]); v[7] = f2bf(hi[3]);
        *(ushort8v*)((char*)sA + dstAswz[i]) = v;
      } else {
        GLOAD_LDS16(srcA16[i] + kt, dstA[i]);
      }
    }
    __syncthreads();
#pragma unroll
    for (int ks = 0; ks < 2; ++ks) {
      short8 af[4], bfr[4];
#pragma unroll
      for (int mi = 0; mi < 4; ++mi) {
        int row = wr * 64 + mi * 16 + cx;
        unsigned off = (unsigned)(row * 128 + ks * 64 + g * 16);
        off ^= (unsigned)((row & 7) << 4);
        af[mi] = *(const short8*)((const char*)sA + off);
      }
#pragma unroll
      for (int ni = 0; ni < 4; ++ni) {
        int row = wc * 64 + ni * 16 + cx;
        unsigned off = (unsigned)(row * 128 + ks * 64 + g * 16);
        off ^= (unsigned)((row & 7) << 4);
        bfr[ni] = *(const short8*)((const char*)sB + off);
      }
#pragma unroll
      for (int mi = 0; mi < 4; ++mi)
#pragma unroll
        for (int ni = 0; ni < 4; ++ni)
          acc[mi][ni] = mfma16(af[mi], bfr[ni], acc[mi][ni]);
    }
    __syncthreads();
  }

  float bv[4];
#pragma unroll
  for (int ni = 0; ni < 4; ++ni)
    bv[ni] = bias[bn * 128 + wc * 64 + ni * 16 + cx];

#pragma unroll
  for (int mi = 0; mi < 4; ++mi)
#pragma unroll
    for (int ni = 0; ni < 4; ++ni) {
      int col = bn * 128 + wc * 64 + ni * 16 + cx;
#pragma unroll
      for (int ri = 0; ri < 4; ++ri) {
        int row = bm * 128 + wr * 64 + mi * 16 + g * 4 + ri;
        float v = acc[mi][ni][ri] + bv[ni];
        if (C_F32)
          ((float*)Cptr)[(size_t)row * ldc + col] = v;
        else
          ((unsigned short*)Cptr)[(size_t)row * ldc + col] = f2bf(v);
      }
    }
}

// ---------------------------------------------------------------------------
// Block-causal flash attention on bf16 qkv, in-place (O overwrites q slice).
// grid: 32 nb * 16 h * 2 halves = 1024 blocks, 4 waves.
// Wave w owns q-frags at half*256 + w*16 + ni*64 (round-robin).
// S^T = mfma(K, Q) so softmax is lane-local (q = lane&15).
// Correctness-first: padded LDS [64][72], plain staging, scalar V gather.
// ---------------------------------------------------------------------------
__global__ __launch_bounds__(256) void attn_block(unsigned short* __restrict__ qkv) {
  const int LDQ = 3072;
  int bid = blockIdx.x;
  int half = bid & 1;
  int nbh = bid >> 1;
  int nb = nbh >> 4, h = nbh & 15;
  int rowblk = nb << 9;
  int tid = threadIdx.x, lane = tid & 63, wave = tid >> 6;
  int g = lane >> 4, cx = lane & 15;

  __shared__ unsigned short sK[64][72];
  __shared__ unsigned short sV[64][72];
  __shared__ unsigned short sP[4][64][72];

  short8 qreg[4][2];
#pragma unroll
  for (int ni = 0; ni < 4; ++ni) {
    int qrow = rowblk + half * 256 + wave * 16 + ni * 64 + cx;
    const unsigned short* qp = qkv + (size_t)qrow * LDQ + h * 64 + g * 8;
    qreg[ni][0] = *(const short8*)qp;
    qreg[ni][1] = *(const short8*)(qp + 32);
  }

  f32x4 zero4 = {0.f, 0.f, 0.f, 0.f};
  f32x4 o[4][4];
#pragma unroll
  for (int a = 0; a < 4; ++a)
#pragma unroll
    for (int b = 0; b < 4; ++b) o[a][b] = zero4;
  float m_run[4], l_run[4];
#pragma unroll
  for (int ni = 0; ni < 4; ++ni) { m_run[ni] = -1e30f; l_run[ni] = 0.f; }

  int ntiles = half ? 8 : 4;
  const float CEXP = 0.125f * 1.44269504088896f;  // SCALE2 * log2(e)

  for (int t = 0; t < ntiles; ++t) {
#pragma unroll
    for (int i = 0; i < 2; ++i) {
      int c = i * 256 + tid;
      int r = c >> 3, c8 = (c & 7) * 8;
      size_t grow = (size_t)(rowblk + t * 64 + r) * LDQ;
      short8 kv8 = *(const short8*)(qkv + grow + 1024 + h * 64 + c8);
      short8 vv8 = *(const short8*)(qkv + grow + 2048 + h * 64 + c8);
      *(short8*)&sK[r][c8] = kv8;
      *(short8*)&sV[r][c8] = vv8;
    }
    __syncthreads();

    // S^T = K * Q   (MFMA rows = k, cols = q)
    f32x4 s[4][4];
#pragma unroll
    for (int a = 0; a < 4; ++a)
#pragma unroll
      for (int b = 0; b < 4; ++b) s[a][b] = zero4;
#pragma unroll
    for (int ks = 0; ks < 2; ++ks) {
      short8 kf[4];
#pragma unroll
      for (int mi = 0; mi < 4; ++mi)
        kf[mi] = *(const short8*)&sK[mi * 16 + cx][ks * 32 + g * 8];
#pragma unroll
      for (int mi = 0; mi < 4; ++mi)
#pragma unroll
        for (int ni = 0; ni < 4; ++ni)
          s[mi][ni] = mfma16(kf[mi], qreg[ni][ks], s[mi][ni]);
    }

    // online softmax per q-frag (lane's q = qbase + (lane&15))
    float rescv[4];
#pragma unroll
    for (int ni = 0; ni < 4; ++ni) {
      int qbase = half * 256 + wave * 16 + ni * 64;
      int qloc = qbase + cx;
      if ((t * 64 + 63) > qbase) {
#pragma unroll
        for (int mi = 0; mi < 4; ++mi)
#pragma unroll
          for (int ri = 0; ri < 4; ++ri) {
            int kk = t * 64 + mi * 16 + g * 4 + ri;
            if (kk > qloc) s[mi][ni][ri] = -3e38f;
          }
      }
      float tm = -3e38f;
#pragma unroll
      for (int mi = 0; mi < 4; ++mi)
        tm = fmaxf(tm, fmaxf(fmaxf(s[mi][ni][0], s[mi][ni][1]),
                             fmaxf(s[mi][ni][2], s[mi][ni][3])));
      tm = fmaxf(tm, __shfl_xor(tm, 16));
      tm = fmaxf(tm, __shfl_xor(tm, 32));
      float mnew = fmaxf(m_run[ni], tm);
      float resc = exp2f((m_run[ni] - mnew) * CEXP);
      float tsum = 0.f;
#pragma unroll
      for (int mi = 0; mi < 4; ++mi)
#pragma unroll
        for (int ri = 0; ri < 4; ++ri) {
          float p = exp2f((s[mi][ni][ri] - mnew) * CEXP);
          s[mi][ni][ri] = p;
          tsum += p;
        }
      tsum += __shfl_xor(tsum, 16);
      tsum += __shfl_xor(tsum, 32);
      l_run[ni] = l_run[ni] * resc + tsum;
      m_run[ni] = mnew;
      rescv[ni] = resc;
    }

    // rescale O (stats at q=lane&15; O rows at g*4+ri)
#pragma unroll
    for (int mq = 0; mq < 4; ++mq)
#pragma unroll
      for (int ri = 0; ri < 4; ++ri) {
        float rs = __shfl(rescv[mq], g * 4 + ri);
#pragma unroll
        for (int nd = 0; nd < 4; ++nd) o[mq][nd][ri] *= rs;
      }

    // P -> per-wave padded LDS (row = local q, col = k)
#pragma unroll
    for (int mi = 0; mi < 4; ++mi)
#pragma unroll
      for (int ni = 0; ni < 4; ++ni) {
        ushort4v pk;
        pk[0] = f2bf(s[mi][ni][0]); pk[1] = f2bf(s[mi][ni][1]);
        pk[2] = f2bf(s[mi][ni][2]); pk[3] = f2bf(s[mi][ni][3]);
        *(ushort4v*)&sP[wave][ni * 16 + cx][mi * 16 + g * 4] = pk;
      }

    // O += P * V  (V fragments gathered scalar from padded row-major LDS)
#pragma unroll
    for (int ks = 0; ks < 2; ++ks) {
      short8 pa[4];
#pragma unroll
      for (int mq = 0; mq < 4; ++mq)
        pa[mq] = *(const short8*)&sP[wave][mq * 16 + cx][ks * 32 + g * 8];
#pragma unroll
      for (int nd = 0; nd < 4; ++nd) {
        short8 vf;
#pragma unroll
        for (int j = 0; j < 8; ++j)
          vf[j] = (short)sV[ks * 32 + g * 8 + j][nd * 16 + cx];
#pragma unroll
        for (int mq = 0; mq < 4; ++mq)
          o[mq][nd] = mfma16(pa[mq], vf, o[mq][nd]);
      }
    }
    __syncthreads();
  }

  // epilogue: O /= l, write bf16 into q slice (wave-owned rows, disjoint)
#pragma unroll
  for (int mq = 0; mq < 4; ++mq) {
    float linv_own = 1.0f / fmaxf(l_run[mq], 1e-30f);
#pragma unroll
    for (int ri = 0; ri < 4; ++ri) {
      float li = __shfl(linv_own, g * 4 + ri);
      int qrow = rowblk + half * 256 + wave * 16 + mq * 64 + g * 4 + ri;
#pragma unroll
      for (int nd = 0; nd < 4; ++nd) {
        int col = h * 64 + nd * 16 + cx;
        qkv[(size_t)qrow * LDQ + col] = f2bf(o[mq][nd][ri] * li);
      }
    }
  }
}

// ---------------------------------------------------------------------------
extern "C" void kernel_launch(void* const* d_in, const int* in_sizes, int n_in,
                              void* d_out, int out_size, void* d_ws, size_t ws_size,
                              hipStream_t stream) {
  const float* x      = (const float*)d_in[0];  // [16384,1024] f32
  const float* w_attn = (const float*)d_in[1];  // [1024,3072]  f32
  const float* b_attn = (const float*)d_in[2];  // [3072]       f32
  const float* w_proj = (const float*)d_in[3];  // [1024,1024]  f32
  const float* b_proj = (const float*)d_in[4];  // [1024]       f32
  float* out = (float*)d_out;                   // [16384,1024] f32

  char* ws = (char*)d_ws;
  unsigned short* qkv = (unsigned short*)ws;                       // bf16 16384*3072
  unsigned short* wAT = (unsigned short*)(ws + (size_t)16384 * 3072 * 2);
  unsigned short* wPT = wAT + (size_t)3072 * 1024;

  // weight transpose+convert: f32 [K,N] -> bf16 [N,K]
  transposeW<<<dim3(48, 16), 256, 0, stream>>>(w_attn, wAT, 1024, 3072);
  transposeW<<<dim3(16, 16), 256, 0, stream>>>(w_proj, wPT, 1024, 1024);

  // qkv = x @ w_attn + b_attn  (A f32 reg-staged, C bf16)  M=16384 N=3072 K=1024
  gemm_bt<true, false><<<128 * 24, 256, 0, stream>>>(
      (const void*)x, 1024, wAT, 1024, b_attn, (void*)qkv, 3072, 24, 1024);

  // block-causal attention in-place on q slice
  attn_block<<<1024, 256, 0, stream>>>(qkv);

  // out = a @ w_proj + b_proj  (A bf16 gload, C f32)  M=16384 N=1024 K=1024
  gemm_bt<false, true><<<128 * 8, 256, 0, stream>>>(
      (const void*)qkv, 3072, wPT, 1024, b_proj, (void*)out, 1024, 8, 1024);
}

// Round 4
// 362.331 us; speedup vs baseline: 1.0448x; 1.0448x over previous
//
#include <hip/hip_runtime.h>
#include <stdint.h>

// FactoredAttention: x[16384,1024] f32 -> (x->bf16) -> qkv GEMM -> 16-block
// causal attn -> proj GEMM -> out f32.  I/O f32; bf16 compute/intermediates.
// ws: qkv bf16 (16384*3072) | w_attnT bf16 (3072*1024) | w_projT bf16 (1024*1024)
// xbf16 (16384*1024, 33.5MB) lives in d_out scratch (dead before GEMM2 writes).

typedef __bf16 bf16x8 __attribute__((ext_vector_type(8)));
typedef short short8 __attribute__((ext_vector_type(8)));
typedef float f32x4 __attribute__((ext_vector_type(4)));
typedef unsigned short ushort4v __attribute__((ext_vector_type(4)));
typedef unsigned short ushort8v __attribute__((ext_vector_type(8)));

#define GLOAD_LDS16(g, l)                                                      \
  __builtin_amdgcn_global_load_lds(                                            \
      (const __attribute__((address_space(1))) void*)(g),                      \
      (__attribute__((address_space(3))) void*)(l), 16, 0, 0)

static __device__ __forceinline__ f32x4 mfma16(short8 a, short8 b, f32x4 c) {
  return __builtin_amdgcn_mfma_f32_16x16x32_bf16(
      __builtin_bit_cast(bf16x8, a), __builtin_bit_cast(bf16x8, b), c, 0, 0, 0);
}

static __device__ __forceinline__ unsigned short f2bf(float f) {
  unsigned u = __builtin_bit_cast(unsigned, f);
  u += 0x7FFFu + ((u >> 16) & 1u);
  return (unsigned short)(u >> 16);
}

// ---------------------------------------------------------------------------
// f32 -> bf16 elementwise convert (vectorized, grid-stride).  n % 8 == 0.
// ---------------------------------------------------------------------------
__global__ __launch_bounds__(256) void convert_bf16(
    const float* __restrict__ in, unsigned short* __restrict__ out, int n8) {
  for (int i = blockIdx.x * 256 + threadIdx.x; i < n8; i += gridDim.x * 256) {
    f32x4 lo = *(const f32x4*)(in + (size_t)i * 8);
    f32x4 hi = *(const f32x4*)(in + (size_t)i * 8 + 4);
    ushort8v v;
    v[0] = f2bf(lo[0]); v[1] = f2bf(lo[1]); v[2] = f2bf(lo[2]); v[3] = f2bf(lo[3]);
    v[4] = f2bf(hi[0]); v[5] = f2bf(hi[1]); v[6] = f2bf(hi[2]); v[7] = f2bf(hi[3]);
    *(ushort8v*)(out + (size_t)i * 8) = v;
  }
}

// ---------------------------------------------------------------------------
// Transpose + convert: in f32 [K][N] -> out bf16 [N][K].  grid (N/64, K/64).
// ---------------------------------------------------------------------------
__global__ __launch_bounds__(256) void transposeW(
    const float* __restrict__ in, unsigned short* __restrict__ out,
    int K, int N) {
  __shared__ float tile[64][68];
  int tn = blockIdx.x * 64, tk = blockIdx.y * 64;
  int tid = threadIdx.x;
#pragma unroll
  for (int i = 0; i < 4; ++i) {
    int ch = i * 256 + tid;
    int r = ch >> 4, c4 = (ch & 15) << 2;
    f32x4 v = *(const f32x4*)(in + (size_t)(tk + r) * N + tn + c4);
    tile[r][c4] = v[0]; tile[r][c4 + 1] = v[1];
    tile[r][c4 + 2] = v[2]; tile[r][c4 + 3] = v[3];
  }
  __syncthreads();
#pragma unroll
  for (int i = 0; i < 4; ++i) {
    int ch = i * 256 + tid;
    int r = ch >> 4, c4 = (ch & 15) << 2;
    ushort4v v;
    v[0] = f2bf(tile[c4][r]);     v[1] = f2bf(tile[c4 + 1][r]);
    v[2] = f2bf(tile[c4 + 2][r]); v[3] = f2bf(tile[c4 + 3][r]);
    *(ushort4v*)(out + (size_t)(tn + r) * K + tk + c4) = v;
  }
}

// ---------------------------------------------------------------------------
// C[M][N] = A[M][K] * Bt[N][K]^T + bias(f32).  A,Bt bf16.  128x128 tile,
// BK=64, 2x2 waves.  Both operands staged via global_load_lds width=16 with
// inverse-swizzled per-lane global source; ds_read_b128 with XOR swizzle
// (byte ^= (row&7)<<4).  C_F32 selects output dtype.  grid.x % 8 == 0.
// ---------------------------------------------------------------------------
template <bool C_F32>
__global__ __launch_bounds__(256) void gemm_bt(
    const unsigned short* __restrict__ A, int lda,
    const unsigned short* __restrict__ Bt, int ldb,
    const float* __restrict__ bias,
    void* __restrict__ Cptr, int ldc,
    int Ntiles, int K) {
  __shared__ unsigned short sA[128 * 64];
  __shared__ unsigned short sB[128 * 64];
  int bid = blockIdx.x;
  int nwg = gridDim.x;
  int swz = (bid & 7) * (nwg >> 3) + (bid >> 3);
  int bm = swz / Ntiles, bn = swz % Ntiles;
  int tid = threadIdx.x;
  int lane = tid & 63, wave = tid >> 6;
  int wr = wave >> 1, wc = wave & 1;
  int g = lane >> 4, cx = lane & 15;

  const unsigned short* srcA[4];
  const unsigned short* srcB[4];
  unsigned short* dstA[4];
  unsigned short* dstB[4];
#pragma unroll
  for (int i = 0; i < 4; ++i) {
    int c = i * 256 + tid;
    int r = c >> 3, pc = c & 7;
    int cc = pc ^ (r & 7);  // inverse-swizzled source chunk
    srcA[i] = A + (size_t)(bm * 128 + r) * lda + cc * 8;
    srcB[i] = Bt + (size_t)(bn * 128 + r) * ldb + cc * 8;
    dstA[i] = sA + (i * 256 + wave * 64) * 8;
    dstB[i] = sB + (i * 256 + wave * 64) * 8;
  }

  f32x4 zero4 = {0.f, 0.f, 0.f, 0.f};
  f32x4 acc[4][4];
#pragma unroll
  for (int a = 0; a < 4; ++a)
#pragma unroll
    for (int b = 0; b < 4; ++b) acc[a][b] = zero4;

  for (int kt = 0; kt < K; kt += 64) {
#pragma unroll
    for (int i = 0; i < 4; ++i) {
      GLOAD_LDS16(srcA[i] + kt, dstA[i]);
      GLOAD_LDS16(srcB[i] + kt, dstB[i]);
    }
    __syncthreads();
#pragma unroll
    for (int ks = 0; ks < 2; ++ks) {
      short8 af[4], bfr[4];
#pragma unroll
      for (int mi = 0; mi < 4; ++mi) {
        int row = wr * 64 + mi * 16 + cx;
        unsigned off = (unsigned)(row * 128 + ks * 64 + g * 16);
        off ^= (unsigned)((row & 7) << 4);
        af[mi] = *(const short8*)((const char*)sA + off);
      }
#pragma unroll
      for (int ni = 0; ni < 4; ++ni) {
        int row = wc * 64 + ni * 16 + cx;
        unsigned off = (unsigned)(row * 128 + ks * 64 + g * 16);
        off ^= (unsigned)((row & 7) << 4);
        bfr[ni] = *(const short8*)((const char*)sB + off);
      }
#pragma unroll
      for (int mi = 0; mi < 4; ++mi)
#pragma unroll
        for (int ni = 0; ni < 4; ++ni)
          acc[mi][ni] = mfma16(af[mi], bfr[ni], acc[mi][ni]);
    }
    __syncthreads();
  }

  float bv[4];
#pragma unroll
  for (int ni = 0; ni < 4; ++ni)
    bv[ni] = bias[bn * 128 + wc * 64 + ni * 16 + cx];

#pragma unroll
  for (int mi = 0; mi < 4; ++mi)
#pragma unroll
    for (int ni = 0; ni < 4; ++ni) {
      int col = bn * 128 + wc * 64 + ni * 16 + cx;
#pragma unroll
      for (int ri = 0; ri < 4; ++ri) {
        int row = bm * 128 + wr * 64 + mi * 16 + g * 4 + ri;
        float v = acc[mi][ni][ri] + bv[ni];
        if (C_F32)
          ((float*)Cptr)[(size_t)row * ldc + col] = v;
        else
          ((unsigned short*)Cptr)[(size_t)row * ldc + col] = f2bf(v);
      }
    }
}

// ---------------------------------------------------------------------------
// Block-causal flash attention on bf16 qkv, in-place (O overwrites q slice).
// grid: 32 nb * 16 h * 2 halves = 1024 blocks, 4 waves.
// Wave w owns q-frags at half*256 + w*16 + ni*64 (round-robin).
// S^T = mfma(K, Q) so softmax is lane-local (q = lane&15).
// ---------------------------------------------------------------------------
__global__ __launch_bounds__(256) void attn_block(unsigned short* __restrict__ qkv) {
  const int LDQ = 3072;
  int bid = blockIdx.x;
  int half = bid & 1;
  int nbh = bid >> 1;
  int nb = nbh >> 4, h = nbh & 15;
  int rowblk = nb << 9;
  int tid = threadIdx.x, lane = tid & 63, wave = tid >> 6;
  int g = lane >> 4, cx = lane & 15;

  __shared__ unsigned short sK[64][72];
  __shared__ unsigned short sV[64][72];
  __shared__ unsigned short sP[4][64][72];

  short8 qreg[4][2];
#pragma unroll
  for (int ni = 0; ni < 4; ++ni) {
    int qrow = rowblk + half * 256 + wave * 16 + ni * 64 + cx;
    const unsigned short* qp = qkv + (size_t)qrow * LDQ + h * 64 + g * 8;
    qreg[ni][0] = *(const short8*)qp;
    qreg[ni][1] = *(const short8*)(qp + 32);
  }

  f32x4 zero4 = {0.f, 0.f, 0.f, 0.f};
  f32x4 o[4][4];
#pragma unroll
  for (int a = 0; a < 4; ++a)
#pragma unroll
    for (int b = 0; b < 4; ++b) o[a][b] = zero4;
  float m_run[4], l_run[4];
#pragma unroll
  for (int ni = 0; ni < 4; ++ni) { m_run[ni] = -1e30f; l_run[ni] = 0.f; }

  int ntiles = half ? 8 : 4;
  const float CEXP = 0.125f * 1.44269504088896f;  // SCALE2 * log2(e)

  for (int t = 0; t < ntiles; ++t) {
#pragma unroll
    for (int i = 0; i < 2; ++i) {
      int c = i * 256 + tid;
      int r = c >> 3, c8 = (c & 7) * 8;
      size_t grow = (size_t)(rowblk + t * 64 + r) * LDQ;
      short8 kv8 = *(const short8*)(qkv + grow + 1024 + h * 64 + c8);
      short8 vv8 = *(const short8*)(qkv + grow + 2048 + h * 64 + c8);
      *(short8*)&sK[r][c8] = kv8;
      *(short8*)&sV[r][c8] = vv8;
    }
    __syncthreads();

    // S^T = K * Q   (MFMA rows = k, cols = q)
    f32x4 s[4][4];
#pragma unroll
    for (int a = 0; a < 4; ++a)
#pragma unroll
      for (int b = 0; b < 4; ++b) s[a][b] = zero4;
#pragma unroll
    for (int ks = 0; ks < 2; ++ks) {
      short8 kf[4];
#pragma unroll
      for (int mi = 0; mi < 4; ++mi)
        kf[mi] = *(const short8*)&sK[mi * 16 + cx][ks * 32 + g * 8];
#pragma unroll
      for (int mi = 0; mi < 4; ++mi)
#pragma unroll
        for (int ni = 0; ni < 4; ++ni)
          s[mi][ni] = mfma16(kf[mi], qreg[ni][ks], s[mi][ni]);
    }

    // online softmax per q-frag (lane's q = qbase + (lane&15))
    float rescv[4];
#pragma unroll
    for (int ni = 0; ni < 4; ++ni) {
      int qbase = half * 256 + wave * 16 + ni * 64;
      int qloc = qbase + cx;
      if ((t * 64 + 63) > qbase) {
#pragma unroll
        for (int mi = 0; mi < 4; ++mi)
#pragma unroll
          for (int ri = 0; ri < 4; ++ri) {
            int kk = t * 64 + mi * 16 + g * 4 + ri;
            if (kk > qloc) s[mi][ni][ri] = -3e38f;
          }
      }
      float tm = -3e38f;
#pragma unroll
      for (int mi = 0; mi < 4; ++mi)
        tm = fmaxf(tm, fmaxf(fmaxf(s[mi][ni][0], s[mi][ni][1]),
                             fmaxf(s[mi][ni][2], s[mi][ni][3])));
      tm = fmaxf(tm, __shfl_xor(tm, 16));
      tm = fmaxf(tm, __shfl_xor(tm, 32));
      float mnew = fmaxf(m_run[ni], tm);
      float resc = exp2f((m_run[ni] - mnew) * CEXP);
      float tsum = 0.f;
#pragma unroll
      for (int mi = 0; mi < 4; ++mi)
#pragma unroll
        for (int ri = 0; ri < 4; ++ri) {
          float p = exp2f((s[mi][ni][ri] - mnew) * CEXP);
          s[mi][ni][ri] = p;
          tsum += p;
        }
      tsum += __shfl_xor(tsum, 16);
      tsum += __shfl_xor(tsum, 32);
      l_run[ni] = l_run[ni] * resc + tsum;
      m_run[ni] = mnew;
      rescv[ni] = resc;
    }

    // rescale O (stats at q=lane&15; O rows at g*4+ri)
#pragma unroll
    for (int mq = 0; mq < 4; ++mq)
#pragma unroll
      for (int ri = 0; ri < 4; ++ri) {
        float rs = __shfl(rescv[mq], g * 4 + ri);
#pragma unroll
        for (int nd = 0; nd < 4; ++nd) o[mq][nd][ri] *= rs;
      }

    // P -> per-wave padded LDS (row = local q, col = k)
#pragma unroll
    for (int mi = 0; mi < 4; ++mi)
#pragma unroll
      for (int ni = 0; ni < 4; ++ni) {
        ushort4v pk;
        pk[0] = f2bf(s[mi][ni][0]); pk[1] = f2bf(s[mi][ni][1]);
        pk[2] = f2bf(s[mi][ni][2]); pk[3] = f2bf(s[mi][ni][3]);
        *(ushort4v*)&sP[wave][ni * 16 + cx][mi * 16 + g * 4] = pk;
      }

    // O += P * V  (V fragments gathered scalar from padded row-major LDS)
#pragma unroll
    for (int ks = 0; ks < 2; ++ks) {
      short8 pa[4];
#pragma unroll
      for (int mq = 0; mq < 4; ++mq)
        pa[mq] = *(const short8*)&sP[wave][mq * 16 + cx][ks * 32 + g * 8];
#pragma unroll
      for (int nd = 0; nd < 4; ++nd) {
        short8 vf;
#pragma unroll
        for (int j = 0; j < 8; ++j)
          vf[j] = (short)sV[ks * 32 + g * 8 + j][nd * 16 + cx];
#pragma unroll
        for (int mq = 0; mq < 4; ++mq)
          o[mq][nd] = mfma16(pa[mq], vf, o[mq][nd]);
      }
    }
    __syncthreads();
  }

  // epilogue: O /= l, write bf16 into q slice (wave-owned rows, disjoint)
#pragma unroll
  for (int mq = 0; mq < 4; ++mq) {
    float linv_own = 1.0f / fmaxf(l_run[mq], 1e-30f);
#pragma unroll
    for (int ri = 0; ri < 4; ++ri) {
      float li = __shfl(linv_own, g * 4 + ri);
      int qrow = rowblk + half * 256 + wave * 16 + mq * 64 + g * 4 + ri;
#pragma unroll
      for (int nd = 0; nd < 4; ++nd) {
        int col = h * 64 + nd * 16 + cx;
        qkv[(size_t)qrow * LDQ + col] = f2bf(o[mq][nd][ri] * li);
      }
    }
  }
}

// ---------------------------------------------------------------------------
extern "C" void kernel_launch(void* const* d_in, const int* in_sizes, int n_in,
                              void* d_out, int out_size, void* d_ws, size_t ws_size,
                              hipStream_t stream) {
  const float* x      = (const float*)d_in[0];  // [16384,1024] f32
  const float* w_attn = (const float*)d_in[1];  // [1024,3072]  f32
  const float* b_attn = (const float*)d_in[2];  // [3072]       f32
  const float* w_proj = (const float*)d_in[3];  // [1024,1024]  f32
  const float* b_proj = (const float*)d_in[4];  // [1024]       f32
  float* out = (float*)d_out;                   // [16384,1024] f32

  char* ws = (char*)d_ws;
  unsigned short* qkv = (unsigned short*)ws;                       // bf16 16384*3072
  unsigned short* wAT = (unsigned short*)(ws + (size_t)16384 * 3072 * 2);
  unsigned short* wPT = wAT + (size_t)3072 * 1024;
  // x-as-bf16 scratch lives in d_out (33.5MB of 67MB); dead before GEMM2 writes.
  unsigned short* xbf = (unsigned short*)d_out;

  transposeW<<<dim3(48, 16), 256, 0, stream>>>(w_attn, wAT, 1024, 3072);
  transposeW<<<dim3(16, 16), 256, 0, stream>>>(w_proj, wPT, 1024, 1024);
  convert_bf16<<<2048, 256, 0, stream>>>(x, xbf, 16384 * 1024 / 8);

  // qkv = x @ w_attn + b_attn  (C bf16)  M=16384 N=3072 K=1024
  gemm_bt<false><<<128 * 24, 256, 0, stream>>>(
      xbf, 1024, wAT, 1024, b_attn, (void*)qkv, 3072, 24, 1024);

  // block-causal attention in-place on q slice
  attn_block<<<1024, 256, 0, stream>>>(qkv);

  // out = a @ w_proj + b_proj  (C f32)  M=16384 N=1024 K=1024
  gemm_bt<true><<<128 * 8, 256, 0, stream>>>(
      qkv, 3072, wPT, 1024, b_proj, (void*)out, 1024, 8, 1024);
}

// Round 5
// 322.282 us; speedup vs baseline: 1.1746x; 1.1243x over previous
//
#include <hip/hip_runtime.h>
#include <stdint.h>

// FactoredAttention: x[16384,1024] f32 -> (x->bf16) -> qkv GEMM -> 16-block
// causal attn -> proj GEMM -> out f32.  I/O f32; bf16 compute/intermediates.
// ws: qkv bf16 (16384*3072) | w_attnT bf16 (3072*1024) | w_projT bf16 (1024*1024)
// xbf16 (33.5MB) lives in d_out scratch (dead before GEMM2 writes it).

typedef __bf16 bf16x8 __attribute__((ext_vector_type(8)));
typedef short short8 __attribute__((ext_vector_type(8)));
typedef float f32x4 __attribute__((ext_vector_type(4)));
typedef unsigned short ushort4v __attribute__((ext_vector_type(4)));
typedef unsigned short ushort8v __attribute__((ext_vector_type(8)));

#define GLOAD_LDS16(g, l)                                                      \
  __builtin_amdgcn_global_load_lds(                                            \
      (const __attribute__((address_space(1))) void*)(g),                      \
      (__attribute__((address_space(3))) void*)(l), 16, 0, 0)

static __device__ __forceinline__ f32x4 mfma16(short8 a, short8 b, f32x4 c) {
  return __builtin_amdgcn_mfma_f32_16x16x32_bf16(
      __builtin_bit_cast(bf16x8, a), __builtin_bit_cast(bf16x8, b), c, 0, 0, 0);
}

static __device__ __forceinline__ unsigned short f2bf(float f) {
  unsigned u = __builtin_bit_cast(unsigned, f);
  u += 0x7FFFu + ((u >> 16) & 1u);
  return (unsigned short)(u >> 16);
}

// ---------------------------------------------------------------------------
// f32 -> bf16 elementwise convert (vectorized, grid-stride).
// ---------------------------------------------------------------------------
__global__ __launch_bounds__(256) void convert_bf16(
    const float* __restrict__ in, unsigned short* __restrict__ out, int n8) {
  for (int i = blockIdx.x * 256 + threadIdx.x; i < n8; i += gridDim.x * 256) {
    f32x4 lo = *(const f32x4*)(in + (size_t)i * 8);
    f32x4 hi = *(const f32x4*)(in + (size_t)i * 8 + 4);
    ushort8v v;
    v[0] = f2bf(lo[0]); v[1] = f2bf(lo[1]); v[2] = f2bf(lo[2]); v[3] = f2bf(lo[3]);
    v[4] = f2bf(hi[0]); v[5] = f2bf(hi[1]); v[6] = f2bf(hi[2]); v[7] = f2bf(hi[3]);
    *(ushort8v*)(out + (size_t)i * 8) = v;
  }
}

// ---------------------------------------------------------------------------
// Transpose + convert: in f32 [K][N] -> out bf16 [N][K].  grid (N/64, K/64).
// ---------------------------------------------------------------------------
__global__ __launch_bounds__(256) void transposeW(
    const float* __restrict__ in, unsigned short* __restrict__ out,
    int K, int N) {
  __shared__ float tile[64][68];
  int tn = blockIdx.x * 64, tk = blockIdx.y * 64;
  int tid = threadIdx.x;
#pragma unroll
  for (int i = 0; i < 4; ++i) {
    int ch = i * 256 + tid;
    int r = ch >> 4, c4 = (ch & 15) << 2;
    f32x4 v = *(const f32x4*)(in + (size_t)(tk + r) * N + tn + c4);
    tile[r][c4] = v[0]; tile[r][c4 + 1] = v[1];
    tile[r][c4 + 2] = v[2]; tile[r][c4 + 3] = v[3];
  }
  __syncthreads();
#pragma unroll
  for (int i = 0; i < 4; ++i) {
    int ch = i * 256 + tid;
    int r = ch >> 4, c4 = (ch & 15) << 2;
    ushort4v v;
    v[0] = f2bf(tile[c4][r]);     v[1] = f2bf(tile[c4 + 1][r]);
    v[2] = f2bf(tile[c4 + 2][r]); v[3] = f2bf(tile[c4 + 3][r]);
    *(ushort4v*)(out + (size_t)(tn + r) * K + tk + c4) = v;
  }
}

// ---------------------------------------------------------------------------
// C[M][N] = A[M][K] * Bt[N][K]^T + bias(f32).  A,Bt bf16.  128x128 tile,
// BK=64, 2x2 waves.  global_load_lds width=16 staging with inverse-swizzled
// source; ds_read_b128 with XOR swizzle (byte ^= (row&7)<<4).  grid.x%8==0.
// ---------------------------------------------------------------------------
template <bool C_F32>
__global__ __launch_bounds__(256) void gemm_bt(
    const unsigned short* __restrict__ A, int lda,
    const unsigned short* __restrict__ Bt, int ldb,
    const float* __restrict__ bias,
    void* __restrict__ Cptr, int ldc,
    int Ntiles, int K) {
  __shared__ unsigned short sA[128 * 64];
  __shared__ unsigned short sB[128 * 64];
  int bid = blockIdx.x;
  int nwg = gridDim.x;
  int swz = (bid & 7) * (nwg >> 3) + (bid >> 3);
  int bm = swz / Ntiles, bn = swz % Ntiles;
  int tid = threadIdx.x;
  int lane = tid & 63, wave = tid >> 6;
  int wr = wave >> 1, wc = wave & 1;
  int g = lane >> 4, cx = lane & 15;

  const unsigned short* srcA[4];
  const unsigned short* srcB[4];
  unsigned short* dstA[4];
  unsigned short* dstB[4];
#pragma unroll
  for (int i = 0; i < 4; ++i) {
    int c = i * 256 + tid;
    int r = c >> 3, pc = c & 7;
    int cc = pc ^ (r & 7);
    srcA[i] = A + (size_t)(bm * 128 + r) * lda + cc * 8;
    srcB[i] = Bt + (size_t)(bn * 128 + r) * ldb + cc * 8;
    dstA[i] = sA + (i * 256 + wave * 64) * 8;
    dstB[i] = sB + (i * 256 + wave * 64) * 8;
  }

  f32x4 zero4 = {0.f, 0.f, 0.f, 0.f};
  f32x4 acc[4][4];
#pragma unroll
  for (int a = 0; a < 4; ++a)
#pragma unroll
    for (int b = 0; b < 4; ++b) acc[a][b] = zero4;

  for (int kt = 0; kt < K; kt += 64) {
#pragma unroll
    for (int i = 0; i < 4; ++i) {
      GLOAD_LDS16(srcA[i] + kt, dstA[i]);
      GLOAD_LDS16(srcB[i] + kt, dstB[i]);
    }
    __syncthreads();
#pragma unroll
    for (int ks = 0; ks < 2; ++ks) {
      short8 af[4], bfr[4];
#pragma unroll
      for (int mi = 0; mi < 4; ++mi) {
        int row = wr * 64 + mi * 16 + cx;
        unsigned off = (unsigned)(row * 128 + ks * 64 + g * 16);
        off ^= (unsigned)((row & 7) << 4);
        af[mi] = *(const short8*)((const char*)sA + off);
      }
#pragma unroll
      for (int ni = 0; ni < 4; ++ni) {
        int row = wc * 64 + ni * 16 + cx;
        unsigned off = (unsigned)(row * 128 + ks * 64 + g * 16);
        off ^= (unsigned)((row & 7) << 4);
        bfr[ni] = *(const short8*)((const char*)sB + off);
      }
#pragma unroll
      for (int mi = 0; mi < 4; ++mi)
#pragma unroll
        for (int ni = 0; ni < 4; ++ni)
          acc[mi][ni] = mfma16(af[mi], bfr[ni], acc[mi][ni]);
    }
    __syncthreads();
  }

  float bv[4];
#pragma unroll
  for (int ni = 0; ni < 4; ++ni)
    bv[ni] = bias[bn * 128 + wc * 64 + ni * 16 + cx];

#pragma unroll
  for (int mi = 0; mi < 4; ++mi)
#pragma unroll
    for (int ni = 0; ni < 4; ++ni) {
      int col = bn * 128 + wc * 64 + ni * 16 + cx;
#pragma unroll
      for (int ri = 0; ri < 4; ++ri) {
        int row = bm * 128 + wr * 64 + mi * 16 + g * 4 + ri;
        float v = acc[mi][ni][ri] + bv[ni];
        if (C_F32)
          ((float*)Cptr)[(size_t)row * ldc + col] = v;
        else
          ((unsigned short*)Cptr)[(size_t)row * ldc + col] = f2bf(v);
      }
    }
}

// ---------------------------------------------------------------------------
// Block-causal flash attention on bf16 qkv, in-place (O overwrites q slice).
// grid: 32 nb * 16 h * 4 q-quarters = 2048 blocks, 4 waves.
// Each block: 128 q rows; wave w owns frags at qs*128 + w*16 + ni*64 (ni=0,1).
// S^T = mfma(K, Q) -> softmax lane-local at q = lane&15.
// PV computed as O^T = mfma(V^T, P^T): V stored transposed in LDS (scatter
// write at staging), P round-trips per-wave LDS.  O^T keeps q = lane&15 ->
// rescale & epilogue fully lane-local (no shfl).
// All LDS tiles: stride-128B rows with XOR swizzle byte^=(row&7)<<4
// (GEMM-verified 0-conflict ds_read_b128 pattern).  LDS total 32KB.
// ---------------------------------------------------------------------------
__global__ __launch_bounds__(256) void attn_block(unsigned short* __restrict__ qkv) {
  const int LDQ = 3072;
  int bid = blockIdx.x;
  int qs = bid & 3;
  int nbh = bid >> 2;
  int nb = nbh >> 4, h = nbh & 15;
  int rowblk = nb << 9;
  int tid = threadIdx.x, lane = tid & 63, wave = tid >> 6;
  int g = lane >> 4, cx = lane & 15;

  __shared__ unsigned short sK[64 * 64];
  __shared__ unsigned short sVT[64 * 64];
  __shared__ unsigned short sP[4][32 * 64];
  unsigned short* myP = sP[wave];

  // Q fragments: q = rowblk + qs*128 + wave*16 + ni*64 + cx
  short8 qreg[2][2];
#pragma unroll
  for (int ni = 0; ni < 2; ++ni) {
    int qrow = rowblk + qs * 128 + wave * 16 + ni * 64 + cx;
    const unsigned short* qp = qkv + (size_t)qrow * LDQ + h * 64 + g * 8;
    qreg[ni][0] = *(const short8*)qp;
    qreg[ni][1] = *(const short8*)(qp + 32);
  }

  f32x4 zero4 = {0.f, 0.f, 0.f, 0.f};
  f32x4 ot[2][4];  // O^T: lane holds O^T[d=nd*16+g*4+ri][q=mq*16+cx frag]
#pragma unroll
  for (int a = 0; a < 2; ++a)
#pragma unroll
    for (int b = 0; b < 4; ++b) ot[a][b] = zero4;
  float m_run[2], l_run[2];
#pragma unroll
  for (int ni = 0; ni < 2; ++ni) { m_run[ni] = -1e30f; l_run[ni] = 0.f; }

  // staging sources: K via gload_lds (inverse-swizzled src); V reg-staged
  const unsigned short* srcK[2];
  unsigned short* dstK[2];
  const unsigned short* srcV[2];
#pragma unroll
  for (int i = 0; i < 2; ++i) {
    int c = i * 256 + tid;
    int r = c >> 3, pc = c & 7, cc = pc ^ (r & 7);
    srcK[i] = qkv + (size_t)(rowblk + r) * LDQ + 1024 + h * 64 + cc * 8;
    dstK[i] = sK + (i * 256 + wave * 64) * 8;
    srcV[i] = qkv + (size_t)(rowblk + r) * LDQ + 2048 + h * 64 + pc * 8;
  }

  int ntiles = 2 * qs + 2;
  const float CEXP = 0.125f * 1.44269504088896f;  // SCALE2 * log2(e)

  for (int t = 0; t < ntiles; ++t) {
    size_t tadv = (size_t)(t * 64) * LDQ;
    // issue V loads + K async staging
    short8 vv0 = *(const short8*)(srcV[0] + tadv);
    short8 vv1 = *(const short8*)(srcV[1] + tadv);
    GLOAD_LDS16(srcK[0] + tadv, dstK[0]);
    GLOAD_LDS16(srcK[1] + tadv, dstK[1]);
    // scatter V^T: element V[k][d] -> byte (d*128 + 2k) ^ ((d&7)<<4)
#pragma unroll
    for (int i = 0; i < 2; ++i) {
      int c = i * 256 + tid;
      int kr = c >> 3, d8 = c & 7;
      short8 vv = i ? vv1 : vv0;
#pragma unroll
      for (int j = 0; j < 8; ++j) {
        unsigned off = (unsigned)((d8 * 8 + j) * 128 + kr * 2) ^ (unsigned)(j << 4);
        *(unsigned short*)((char*)sVT + off) = (unsigned short)vv[j];
      }
    }
    __syncthreads();

    // S^T = K * Q^T  (rows k, cols q)
    f32x4 s[4][2];
#pragma unroll
    for (int a = 0; a < 4; ++a)
#pragma unroll
      for (int b = 0; b < 2; ++b) s[a][b] = zero4;
#pragma unroll
    for (int ks = 0; ks < 2; ++ks) {
      short8 kf[4];
#pragma unroll
      for (int mi = 0; mi < 4; ++mi) {
        int row = mi * 16 + cx;
        unsigned off = (unsigned)(row * 128 + ks * 64 + g * 16);
        off ^= (unsigned)((row & 7) << 4);
        kf[mi] = *(const short8*)((const char*)sK + off);
      }
#pragma unroll
      for (int mi = 0; mi < 4; ++mi)
#pragma unroll
        for (int ni = 0; ni < 2; ++ni)
          s[mi][ni] = mfma16(kf[mi], qreg[ni][ks], s[mi][ni]);
    }

    // online softmax per q-frag (lane's q = qbase + cx)
    float rescv[2];
#pragma unroll
    for (int ni = 0; ni < 2; ++ni) {
      int qbase = qs * 128 + wave * 16 + ni * 64;
      int qloc = qbase + cx;
      if ((t * 64 + 63) > qbase) {
#pragma unroll
        for (int mi = 0; mi < 4; ++mi)
#pragma unroll
          for (int ri = 0; ri < 4; ++ri) {
            int kk = t * 64 + mi * 16 + g * 4 + ri;
            if (kk > qloc) s[mi][ni][ri] = -3e38f;
          }
      }
      float tm = -3e38f;
#pragma unroll
      for (int mi = 0; mi < 4; ++mi)
        tm = fmaxf(tm, fmaxf(fmaxf(s[mi][ni][0], s[mi][ni][1]),
                             fmaxf(s[mi][ni][2], s[mi][ni][3])));
      tm = fmaxf(tm, __shfl_xor(tm, 16));
      tm = fmaxf(tm, __shfl_xor(tm, 32));
      float mnew = fmaxf(m_run[ni], tm);
      float resc = exp2f((m_run[ni] - mnew) * CEXP);
      float tsum = 0.f;
#pragma unroll
      for (int mi = 0; mi < 4; ++mi)
#pragma unroll
        for (int ri = 0; ri < 4; ++ri) {
          float p = exp2f((s[mi][ni][ri] - mnew) * CEXP);
          s[mi][ni][ri] = p;
          tsum += p;
        }
      tsum += __shfl_xor(tsum, 16);
      tsum += __shfl_xor(tsum, 32);
      l_run[ni] = l_run[ni] * resc + tsum;
      m_run[ni] = mnew;
      rescv[ni] = resc;
    }

    // rescale O^T — lane-local (all elems share q = mq-frag + cx)
#pragma unroll
    for (int mq = 0; mq < 2; ++mq)
#pragma unroll
      for (int nd = 0; nd < 4; ++nd) {
        ot[mq][nd][0] *= rescv[mq]; ot[mq][nd][1] *= rescv[mq];
        ot[mq][nd][2] *= rescv[mq]; ot[mq][nd][3] *= rescv[mq];
      }

    // P -> per-wave LDS as [q32][k64] swizzled (lane holds P[q=ni*16+cx][k])
#pragma unroll
    for (int mi = 0; mi < 4; ++mi)
#pragma unroll
      for (int ni = 0; ni < 2; ++ni) {
        ushort4v pk;
        pk[0] = f2bf(s[mi][ni][0]); pk[1] = f2bf(s[mi][ni][1]);
        pk[2] = f2bf(s[mi][ni][2]); pk[3] = f2bf(s[mi][ni][3]);
        int row = ni * 16 + cx;
        unsigned off = (unsigned)(row * 128 + mi * 32 + g * 8);
        off ^= (unsigned)((row & 7) << 4);
        *(ushort4v*)((char*)myP + off) = pk;
      }

    // O^T += V^T * P^T   (a = V^T rows from sVT, b = P rows from myP)
#pragma unroll
    for (int ks = 0; ks < 2; ++ks) {
      short8 pb[2];
#pragma unroll
      for (int mq = 0; mq < 2; ++mq) {
        int row = mq * 16 + cx;
        unsigned off = (unsigned)(row * 128 + ks * 64 + g * 16);
        off ^= (unsigned)((row & 7) << 4);
        pb[mq] = *(const short8*)((const char*)myP + off);
      }
      short8 vf[4];
#pragma unroll
      for (int nd = 0; nd < 4; ++nd) {
        int row = nd * 16 + cx;
        unsigned off = (unsigned)(row * 128 + ks * 64 + g * 16);
        off ^= (unsigned)((row & 7) << 4);
        vf[nd] = *(const short8*)((const char*)sVT + off);
      }
#pragma unroll
      for (int mq = 0; mq < 2; ++mq)
#pragma unroll
        for (int nd = 0; nd < 4; ++nd)
          ot[mq][nd] = mfma16(vf[nd], pb[mq], ot[mq][nd]);
    }
    __syncthreads();
  }

  // epilogue: O^T /= l — fully lane-local; ushort4 stores
#pragma unroll
  for (int mq = 0; mq < 2; ++mq) {
    float linv = 1.0f / fmaxf(l_run[mq], 1e-30f);
    int qrow = rowblk + qs * 128 + wave * 16 + mq * 64 + cx;
#pragma unroll
    for (int nd = 0; nd < 4; ++nd) {
      ushort4v w4;
      w4[0] = f2bf(ot[mq][nd][0] * linv); w4[1] = f2bf(ot[mq][nd][1] * linv);
      w4[2] = f2bf(ot[mq][nd][2] * linv); w4[3] = f2bf(ot[mq][nd][3] * linv);
      int col = h * 64 + nd * 16 + g * 4;
      *(ushort4v*)(qkv + (size_t)qrow * LDQ + col) = w4;
    }
  }
}

// ---------------------------------------------------------------------------
extern "C" void kernel_launch(void* const* d_in, const int* in_sizes, int n_in,
                              void* d_out, int out_size, void* d_ws, size_t ws_size,
                              hipStream_t stream) {
  const float* x      = (const float*)d_in[0];  // [16384,1024] f32
  const float* w_attn = (const float*)d_in[1];  // [1024,3072]  f32
  const float* b_attn = (const float*)d_in[2];  // [3072]       f32
  const float* w_proj = (const float*)d_in[3];  // [1024,1024]  f32
  const float* b_proj = (const float*)d_in[4];  // [1024]       f32
  float* out = (float*)d_out;                   // [16384,1024] f32

  char* ws = (char*)d_ws;
  unsigned short* qkv = (unsigned short*)ws;                       // bf16 16384*3072
  unsigned short* wAT = (unsigned short*)(ws + (size_t)16384 * 3072 * 2);
  unsigned short* wPT = wAT + (size_t)3072 * 1024;
  unsigned short* xbf = (unsigned short*)d_out;  // scratch, dead before GEMM2

  transposeW<<<dim3(48, 16), 256, 0, stream>>>(w_attn, wAT, 1024, 3072);
  transposeW<<<dim3(16, 16), 256, 0, stream>>>(w_proj, wPT, 1024, 1024);
  convert_bf16<<<2048, 256, 0, stream>>>(x, xbf, 16384 * 1024 / 8);

  // qkv = x @ w_attn + b_attn  (C bf16)  M=16384 N=3072 K=1024
  gemm_bt<false><<<128 * 24, 256, 0, stream>>>(
      xbf, 1024, wAT, 1024, b_attn, (void*)qkv, 3072, 24, 1024);

  // block-causal attention in-place on q slice (2048 blocks, 4 q-quarters)
  attn_block<<<2048, 256, 0, stream>>>(qkv);

  // out = a @ w_proj + b_proj  (C f32)  M=16384 N=1024 K=1024
  gemm_bt<true><<<128 * 8, 256, 0, stream>>>(
      qkv, 3072, wPT, 1024, b_proj, (void*)out, 1024, 8, 1024);
}